// Round 6
// baseline (452.701 us; speedup 1.0000x reference)
//
#include <hip/hip_runtime.h>
#include <hip/hip_bf16.h>
#include <math.h>

#define NEG_SLOPE 0.2f

typedef __attribute__((ext_vector_type(4))) float f32x4;
typedef __attribute__((ext_vector_type(8))) short bf16x8;
typedef __attribute__((ext_vector_type(4))) short bf16x4;

__device__ __forceinline__ float leaky(float x) { return x > 0.f ? x : NEG_SLOPE * x; }

__device__ __forceinline__ unsigned short bf_hi(float x) {
  return (unsigned short)(__float_as_uint(x) >> 16);  // truncation split (exact residual)
}

__device__ __forceinline__ unsigned short bf_rne(float x) {
  unsigned u = __float_as_uint(x);
  return (unsigned short)((u + 0x7FFFu + ((u >> 16) & 1u)) >> 16);  // round-nearest-even
}

// ---------------- CSR build: bucket-local, fixed-capacity staging ----------------

#define BIN_CHUNK 2048
#define BCAP 8192

__global__ void k_curinit(int* __restrict__ cursor, int NB, float* __restrict__ DEN, int N) {
  int i = blockIdx.x * blockDim.x + threadIdx.x;
  if (i < NB) cursor[i] = i * BCAP;
  if (i < N) DEN[i] = 0.f;                         // workspace is poisoned; must zero
}

// stage edges bucket-contiguously; entry = (src | dstlow<<24, weight_bits).
// FUSED layer-1 coefficient: this kernel is occupancy-rich (3.2 blocks/CU) so the
// L2-hot S[src]/D[dst] gathers + exp hide under the LDS histogram phase.
// stagedEx[pos] = ex*w rides along; DEN[dst] += ex via global f32 atomics.
__global__ __launch_bounds__(256)
void k_bin(const int* __restrict__ ei, const float* __restrict__ ew, int E, int N,
           const float* __restrict__ S, const float* __restrict__ D,
           int* __restrict__ cursor, int2* __restrict__ staged,
           float* __restrict__ stagedEx, float* __restrict__ DEN, int NB) {
  __shared__ int lhist[512];
  __shared__ int lbase[512];
  int tid = threadIdx.x;
  int start = blockIdx.x * BIN_CHUNK;
  int NT = E + N;
  int srcv[8], dstv[8]; float wv[8];
#pragma unroll
  for (int j = 0; j < 8; j++) {
    int e = start + j * 256 + tid;       // coalesced
    int s = 0, d = -1; float w = 0.f;
    if (e < NT) {
      if (e < E) { s = ei[e]; d = ei[E + e]; w = ew[e]; }
      else       { s = d = e - E; w = 1.f; }   // self-loop
    }
    srcv[j] = s; dstv[j] = d; wv[j] = w;
  }
  // issue score gathers early (L2-resident 400KB tables); latency overlaps hist phase
  float sg[8], dg[8];
#pragma unroll
  for (int j = 0; j < 8; j++) {
    int si = (dstv[j] >= 0) ? srcv[j] : 0;
    int di = (dstv[j] >= 0) ? dstv[j] : 0;
    sg[j] = S[si]; dg[j] = D[di];
  }
  for (int b = tid; b < NB; b += 256) lhist[b] = 0;
  __syncthreads();
#pragma unroll
  for (int j = 0; j < 8; j++)
    if (dstv[j] >= 0) atomicAdd(&lhist[dstv[j] >> 8], 1);
  __syncthreads();
  for (int b = tid; b < NB; b += 256) {
    int n = lhist[b];
    lbase[b] = (n > 0) ? atomicAdd(&cursor[b], n) : 0;
    lhist[b] = 0;
  }
  __syncthreads();
  float exv[8];
#pragma unroll
  for (int j = 0; j < 8; j++) exv[j] = __expf(leaky(sg[j] + dg[j]));
#pragma unroll
  for (int j = 0; j < 8; j++) {
    if (dstv[j] >= 0) {
      int bkt = dstv[j] >> 8;
      int off = atomicAdd(&lhist[bkt], 1);          // LDS cursor
      int pos = lbase[bkt] + off;
      staged[pos] = make_int2(srcv[j] | ((dstv[j] & 255) << 24), __float_as_int(wv[j]));
      stagedEx[pos] = exv[j] * wv[j];
      atomicAdd(&DEN[dstv[j]], exv[j]);             // low contention (~16/node), L2-hot
    }
  }
}

// totals from cursor deltas -> parallel exclusive scan -> packed bases
__global__ __launch_bounds__(512)
void k_bscan(const int* __restrict__ cursor, int NB, int NT, int N,
             int* __restrict__ bbase, int* __restrict__ rp) {
  __shared__ int sm[512];
  int tid = threadIdx.x;                           // 512 threads, NB <= 512
  int v = (tid < NB) ? cursor[tid] - tid * BCAP : 0;
  sm[tid] = v;
  __syncthreads();
  for (int off = 1; off < 512; off <<= 1) {        // Hillis-Steele inclusive
    int x = sm[tid];
    int a = (tid >= off) ? sm[tid - off] : 0;
    __syncthreads();
    sm[tid] = x + a;
    __syncthreads();
  }
  if (tid < NB) bbase[tid] = sm[tid] - v;          // exclusive
  if (tid == 0) { bbase[NB] = sm[NB - 1]; rp[N] = NT; }
}

// one block per bucket: LDS count -> scan -> rp -> LDS-cursor scatter to packed csr.
// Scatter loop mechanics identical to R4: no gathers, no exp, no float atomics —
// just one extra coalesced stagedEx read and one extra csrA write.
__global__ __launch_bounds__(512)
void k_finalize(const int2* __restrict__ staged, const float* __restrict__ stagedEx,
                const int* __restrict__ bbase, int N, int* __restrict__ rp,
                int2* __restrict__ csrA, int2* __restrict__ csrB) {
  __shared__ int cnt[256];
  __shared__ int sm[256];
  int b = blockIdx.x, tid = threadIdx.x;
  int sbase = b * BCAP;
  int cbase = bbase[b];
  int size = bbase[b + 1] - cbase;
  if (tid < 256) cnt[tid] = 0;
  __syncthreads();
  for (int i = tid; i < size; i += 512) {
    int2 v = staged[sbase + i];
    atomicAdd(&cnt[((unsigned)v.x) >> 24], 1);
  }
  __syncthreads();
  int s = 0;
  if (tid < 256) { s = cnt[tid]; sm[tid] = s; }
  __syncthreads();
  for (int off = 1; off < 256; off <<= 1) {        // Hillis-Steele inclusive scan
    int x = 0;
    if (tid < 256) { x = sm[tid]; if (tid >= off) x += sm[tid - off]; }
    __syncthreads();
    if (tid < 256) sm[tid] = x;
    __syncthreads();
  }
  if (tid < 256) {
    int excl = sm[tid] - s;
    int node = (b << 8) + tid;
    if (node < N) rp[node] = cbase + excl;
    cnt[tid] = excl;                               // becomes the scatter cursor
  }
  __syncthreads();
  for (int i = tid; i < size; i += 512) {
    int2 v = staged[sbase + i];
    float exw = stagedEx[sbase + i];
    int dlow = ((unsigned)v.x) >> 24;
    int src = v.x & 0x00FFFFFF;
    int pos = cbase + atomicAdd(&cnt[dlow], 1);    // LDS atomic
    csrB[pos] = make_int2(src, v.y);               // (src, w)    for layer 2
    csrA[pos] = make_int2(src, __float_as_int(exw)); // (src, ex*w) for layer 1
  }
}

// ---------------- merged weight prep: W1/W2 bf16 hi/lo images + w2s/w2d vectors ------
__device__ __forceinline__ void wprep_one(const float* __restrict__ W, int idx, int Mout,
                                          unsigned short* __restrict__ whi,
                                          unsigned short* __restrict__ wlo) {
  int k = idx >> 6, n = idx & 63;
  float v = (n < Mout) ? W[(size_t)k * Mout + n] : 0.f;
  unsigned short h = bf_hi(v);
  float hf = __uint_as_float((unsigned)h << 16);
  unsigned short l = bf_hi(v - hf);
  int kc = k >> 5, kk = k & 31, quad = kk >> 3, j = kk & 7;
  int ct = n >> 4, nn = n & 15;
  int off = (((kc * 4 + ct) * 64) + quad * 16 + nn) * 8 + j;
  whi[off] = h; wlo[off] = l;
}

__global__ __launch_bounds__(256)
void k_prep(const float* __restrict__ W1, const float* __restrict__ W2,
            const float* __restrict__ a2s, const float* __restrict__ a2d,
            int FIN, int HID, int NC,
            unsigned short* __restrict__ whi1, unsigned short* __restrict__ wlo1,
            unsigned short* __restrict__ whi2, unsigned short* __restrict__ wlo2,
            float* __restrict__ w2s, float* __restrict__ w2d) {
  int blk = blockIdx.x, tid = threadIdx.x;
  int nb1 = (FIN * 64) >> 8;                       // 64 blocks for W1
  int nb2 = (HID * 64) >> 8;                       // 16 blocks for W2
  if (blk < nb1) {
    wprep_one(W1, blk * 256 + tid, HID, whi1, wlo1);
  } else if (blk < nb1 + nb2) {
    wprep_one(W2, (blk - nb1) * 256 + tid, NC, whi2, wlo2);
  } else {
    if (tid < HID) {                               // w2s = W2@a2s, w2d = W2@a2d
      float s = 0.f, d = 0.f;
      for (int n = 0; n < NC; n++) {
        float w = W2[(size_t)tid * NC + n];
        s += w * a2s[n]; d += w * a2d[n];
      }
      w2s[tid] = s; w2d[tid] = d;
    }
  }
}

// ---------------- MFMA GEMM (split-bf16) + fused attention scores ----------------
// Writes H either f32 (Hf) or RNE bf16 (Hb), row stride ldH, cols < Mout only.
__global__ __launch_bounds__(256)
void k_gemm_mfma(const float* __restrict__ X, int K,
                 const unsigned short* __restrict__ WHI, const unsigned short* __restrict__ WLO,
                 const float* __restrict__ ASRC, const float* __restrict__ ADST, int Mout,
                 float* __restrict__ Hf, unsigned short* __restrict__ Hb, int ldH,
                 float* __restrict__ S, float* __restrict__ D, int N) {
  __shared__ __align__(16) unsigned short xhi[2048], xlo[2048];   // 4 rowtiles*64 lanes*8
  __shared__ __align__(16) unsigned short whs[2048], wls[2048];   // 4 coltiles*64 lanes*8
  int tid = threadIdx.x;
  int lane = tid & 63, w = tid >> 6;
  int rowBase = blockIdx.x * 64;

  f32x4 acc[4];
#pragma unroll
  for (int c = 0; c < 4; c++) acc[c] = (f32x4){0.f, 0.f, 0.f, 0.f};

  int q0 = tid, q1 = tid + 256;
  int row0 = q0 >> 3, k40 = (q0 & 7) << 2;
  int row1 = q1 >> 3, k41 = (q1 & 7) << 2;
  int xo0 = (((row0 >> 4) * 64) + (k40 >> 3) * 16 + (row0 & 15)) * 8 + (k40 & 7);
  int xo1 = (((row1 >> 4) * 64) + (k41 >> 3) * 16 + (row1 & 15)) * 8 + (k41 & 7);
  int grow0 = rowBase + row0, grow1 = rowBase + row1;

  int nch = K >> 5;
  f32x4 xr0, xr1; bf16x8 wh, wl;

  xr0 = (f32x4){0.f, 0.f, 0.f, 0.f}; xr1 = xr0;
  if (grow0 < N) xr0 = *(const f32x4*)&X[(size_t)grow0 * K + k40];
  if (grow1 < N) xr1 = *(const f32x4*)&X[(size_t)grow1 * K + k41];
  wh = *(const bf16x8*)(WHI + tid * 8);
  wl = *(const bf16x8*)(WLO + tid * 8);

  for (int kc = 0; kc < nch; kc++) {
    bf16x4 h4, l4;
#pragma unroll
    for (int i = 0; i < 4; i++) {
      unsigned short h = bf_hi(xr0[i]);
      float hf = __uint_as_float((unsigned)h << 16);
      h4[i] = (short)h; l4[i] = (short)bf_hi(xr0[i] - hf);
    }
    *(bf16x4*)(xhi + xo0) = h4; *(bf16x4*)(xlo + xo0) = l4;
#pragma unroll
    for (int i = 0; i < 4; i++) {
      unsigned short h = bf_hi(xr1[i]);
      float hf = __uint_as_float((unsigned)h << 16);
      h4[i] = (short)h; l4[i] = (short)bf_hi(xr1[i] - hf);
    }
    *(bf16x4*)(xhi + xo1) = h4; *(bf16x4*)(xlo + xo1) = l4;
    *(bf16x8*)(whs + tid * 8) = wh;
    *(bf16x8*)(wls + tid * 8) = wl;
    __syncthreads();

    if (kc + 1 < nch) {
      int kb = (kc + 1) << 5;
      xr0 = (f32x4){0.f, 0.f, 0.f, 0.f}; xr1 = xr0;
      if (grow0 < N) xr0 = *(const f32x4*)&X[(size_t)grow0 * K + kb + k40];
      if (grow1 < N) xr1 = *(const f32x4*)&X[(size_t)grow1 * K + kb + k41];
      wh = *(const bf16x8*)(WHI + (size_t)(kc + 1) * 2048 + tid * 8);
      wl = *(const bf16x8*)(WLO + (size_t)(kc + 1) * 2048 + tid * 8);
    }

    bf16x8 ah = *(const bf16x8*)(xhi + (w * 64 + lane) * 8);
    bf16x8 al = *(const bf16x8*)(xlo + (w * 64 + lane) * 8);
#pragma unroll
    for (int c = 0; c < 4; c++) {
      bf16x8 bh = *(const bf16x8*)(whs + (c * 64 + lane) * 8);
      bf16x8 bl = *(const bf16x8*)(wls + (c * 64 + lane) * 8);
      acc[c] = __builtin_amdgcn_mfma_f32_16x16x32_bf16(ah, bh, acc[c], 0, 0, 0);
      acc[c] = __builtin_amdgcn_mfma_f32_16x16x32_bf16(ah, bl, acc[c], 0, 0, 0);
      acc[c] = __builtin_amdgcn_mfma_f32_16x16x32_bf16(al, bh, acc[c], 0, 0, 0);
    }
    __syncthreads();
  }

  int nn = lane & 15, quad = lane >> 4;
  float as_[4], ad_[4];
#pragma unroll
  for (int c = 0; c < 4; c++) {
    int col = c * 16 + nn;
    as_[c] = (col < Mout) ? ASRC[col] : 0.f;
    ad_[c] = (col < Mout) ? ADST[col] : 0.f;
  }
#pragma unroll
  for (int r = 0; r < 4; r++) {
    int grow = rowBase + w * 16 + quad * 4 + r;
    float ps = 0.f, pd = 0.f;
#pragma unroll
    for (int c = 0; c < 4; c++) {
      float v = acc[c][r];
      int col = c * 16 + nn;
      if (grow < N && col < Mout) {
        if (Hb) Hb[(size_t)grow * ldH + col] = bf_rne(v);
        else    Hf[(size_t)grow * ldH + col] = v;
      }
      ps += v * as_[c]; pd += v * ad_[c];
    }
#pragma unroll
    for (int off = 1; off < 16; off <<= 1) {
      ps += __shfl_xor(ps, off);
      pd += __shfl_xor(pd, off);
    }
    if (nn == 0 && grow < N) { S[grow] = ps; D[grow] = pd; }
  }
}

// ---------------- fused aggregation (R4 body shape) ----------------------------------
// 4 nodes per wave, 16 lanes each, 64 bf16 cols per row (1 cache line per edge).
// COEF=true  (layer 1): csr payload is precomputed ex*w; denominator preloaded from
//                       DEN -> loop body is a PURE gather-FMA (shortest dep chain).
// COEF=false (layer 2): in-loop ex = exp(leaky(Sc[src]+Dc[node])), den accumulated.
// csr meta for window t+1 prefetched while window t computes (R4's measured-best).
// All loads unconditional with clamped-safe addresses; masking on values only.
template <bool COEF, bool OUTB16, bool RELU, bool SCORES>
__global__ __launch_bounds__(256)
void k_agg(const int* __restrict__ rp, const int2* __restrict__ csr,
           const float* __restrict__ Sc, const float* __restrict__ Dc,
           const float* __restrict__ DEN, const unsigned short* __restrict__ Hb,
           void* __restrict__ OutV,
           const float* __restrict__ WS, const float* __restrict__ WD,
           float* __restrict__ S2, float* __restrict__ D2, int N) {
  int gw = (blockIdx.x * blockDim.x + threadIdx.x) >> 6;
  int lane = threadIdx.x & 63;
  int sub = lane >> 4, fl = lane & 15;
  int node = gw * 4 + sub;
  bool active = node < N;
  int b = 0, e = 1; float dd = 0.f, dpre = 1.f;
  if (active) {
    b = rp[node]; e = rp[node + 1];
    if (COEF) dpre = DEN[node];      // used only in epilogue; latency fully hidden
    else      dd = Dc[node];
  }
  float den = 0.f;
  f32x4 acc0 = (f32x4){0.f, 0.f, 0.f, 0.f};
  f32x4 acc1 = (f32x4){0.f, 0.f, 0.f, 0.f};

  int need = e - b;
  need = max(need, __shfl_xor(need, 16));
  need = max(need, __shfl_xor(need, 32));
  int iters = (need + 3) >> 2;
  int last = e - 1;

  // preload window-0 meta
  int idx[4]; float wgt[4];
  int t = b;
#pragma unroll
  for (int j = 0; j < 4; j++) {
    int tj = (t + j < e) ? t + j : last;            // clamped-safe, warm line
    int2 p = csr[tj];
    idx[j] = p.x;
    wgt[j] = (t + j < e) ? __int_as_float(p.y) : 0.f;
  }

  for (int it = 0; it < iters; it++, t += 4) {
    // scores for current window (layer 2 only; S2 table 400KB -> L2-hot)
    float sv[4];
    if (!COEF) {
#pragma unroll
      for (int j = 0; j < 4; j++) sv[j] = Sc[idx[j]];
    }
    // H row gathers for current window: unconditional, 8B/lane, 128B/row
    f32x4 hv[4];
#pragma unroll
    for (int j = 0; j < 4; j++) {
      ushort4 uv = *(const ushort4*)(Hb + (size_t)idx[j] * 64 + (fl << 2));
      hv[j][0] = __uint_as_float((unsigned)uv.x << 16);
      hv[j][1] = __uint_as_float((unsigned)uv.y << 16);
      hv[j][2] = __uint_as_float((unsigned)uv.z << 16);
      hv[j][3] = __uint_as_float((unsigned)uv.w << 16);
    }
    // prefetch next window's csr meta (clamped-safe; dummy on last iter)
    int idn[4]; float wgn[4];
#pragma unroll
    for (int j = 0; j < 4; j++) {
      int tj = (t + 4 + j < e) ? t + 4 + j : last;
      int2 p = csr[tj];
      idn[j] = p.x;
      wgn[j] = (t + 4 + j < e) ? __int_as_float(p.y) : 0.f;
    }
    // compute current window
    float cf[4];
    if (COEF) {
#pragma unroll
      for (int j = 0; j < 4; j++) cf[j] = wgt[j];   // ex*w; tail slots carry 0
    } else {
      float ex[4];
#pragma unroll
      for (int j = 0; j < 4; j++)
        ex[j] = (t + j < e) ? __expf(leaky(sv[j] + dd)) : 0.f;
      den += (ex[0] + ex[1]) + (ex[2] + ex[3]);
#pragma unroll
      for (int j = 0; j < 4; j++) cf[j] = ex[j] * wgt[j];
    }
    acc0 += hv[0] * cf[0] + hv[1] * cf[1];
    acc1 += hv[2] * cf[2] + hv[3] * cf[3];
    // rotate meta
#pragma unroll
    for (int j = 0; j < 4; j++) { idx[j] = idn[j]; wgt[j] = wgn[j]; }
  }

  float dv = COEF ? dpre : den;
  float inv = 1.0f / fmaxf(dv, 1e-16f);
  f32x4 o = (acc0 + acc1) * inv;
  if (RELU) {
#pragma unroll
    for (int j = 0; j < 4; j++) o[j] = fmaxf(o[j], 0.f);
  }
  if (SCORES) {                                    // layer-2 scores from f32 values
    f32x4 ws = *(const f32x4*)&WS[fl << 2];
    f32x4 wd = *(const f32x4*)&WD[fl << 2];
    float ps = o[0] * ws[0] + o[1] * ws[1] + o[2] * ws[2] + o[3] * ws[3];
    float pd = o[0] * wd[0] + o[1] * wd[1] + o[2] * wd[2] + o[3] * wd[3];
#pragma unroll
    for (int off = 1; off < 16; off <<= 1) {
      ps += __shfl_xor(ps, off);
      pd += __shfl_xor(pd, off);
    }
    if (active && fl == 0) { S2[node] = ps; D2[node] = pd; }
  }
  if (active) {
    if (OUTB16) {
      ushort4 st;
      st.x = bf_rne(o[0]); st.y = bf_rne(o[1]); st.z = bf_rne(o[2]); st.w = bf_rne(o[3]);
      *(ushort4*)((unsigned short*)OutV + (size_t)node * 64 + (fl << 2)) = st;
    } else {
      *(f32x4*)((float*)OutV + (size_t)node * 64 + (fl << 2)) = o;
    }
  }
}

// ---------------- launch ----------------
extern "C" void kernel_launch(void* const* d_in, const int* in_sizes, int n_in,
                              void* d_out, int out_size, void* d_ws, size_t ws_size,
                              hipStream_t stream) {
  const float* x   = (const float*)d_in[0];
  const int*   ei  = (const int*)d_in[1];
  const float* ew  = (const float*)d_in[2];
  const float* W1  = (const float*)d_in[3];
  const float* a1s = (const float*)d_in[4];
  const float* a1d = (const float*)d_in[5];
  const float* W2  = (const float*)d_in[6];
  const float* a2s = (const float*)d_in[7];
  const float* a2d = (const float*)d_in[8];

  const int HID = in_sizes[4];            // 64
  const int NC  = in_sizes[7];            // 40
  const int FIN = in_sizes[3] / HID;      // 256
  const int N   = in_sizes[0] / FIN;      // 100000
  const int E   = in_sizes[2];            // 1600000
  const int NT  = E + N;
  const int NB  = (N + 255) >> 8;         // 391 buckets
  float* out = (float*)d_out;

  char* wsb = (char*)d_ws;
  size_t off = 0;
  auto alloc = [&](size_t bytes) -> char* {
    char* p = wsb + off;
    off += (bytes + 255) & ~(size_t)255;
    return p;
  };
  unsigned short* h1b = (unsigned short*)alloc((size_t)N * 64 * 2);  // layer-1 bf16 image
  unsigned short* h2b = (unsigned short*)alloc((size_t)N * 64 * 2);  // layer-2 bf16 image
  float* A      = (float*)alloc((size_t)N * 64 * 4);   // layer-2 aggregated (pre-W2)
  float* S      = (float*)alloc((size_t)N * 4);
  float* D      = (float*)alloc((size_t)N * 4);
  float* S2     = (float*)alloc((size_t)N * 4);
  float* D2     = (float*)alloc((size_t)N * 4);
  float* DEN    = (float*)alloc((size_t)N * 4);
  int*   rp     = (int*)alloc((size_t)(N + 1) * 4);
  int*   bbase  = (int*)alloc((size_t)(NB + 1) * 4);
  int*   cursor = (int*)alloc((size_t)NB * 4);
  int2*  csrA   = (int2*)alloc((size_t)NT * 8);    // (src, ex*w) for layer 1
  int2*  csrB   = (int2*)alloc((size_t)NT * 8);    // (src, w)    for layer 2
  int2*  staged = (int2*)alloc((size_t)NB * BCAP * 8);
  float* stagedEx = (float*)alloc((size_t)NB * BCAP * 4);
  unsigned short* whi1 = (unsigned short*)alloc((size_t)FIN * 64 * 2);
  unsigned short* wlo1 = (unsigned short*)alloc((size_t)FIN * 64 * 2);
  unsigned short* whi2 = (unsigned short*)alloc((size_t)HID * 64 * 2);
  unsigned short* wlo2 = (unsigned short*)alloc((size_t)HID * 64 * 2);
  float* w2s = (float*)alloc((size_t)HID * 4);
  float* w2d = (float*)alloc((size_t)HID * 4);
  (void)ws_size; (void)n_in; (void)out_size;

  const int ebins = (NT + BIN_CHUNK - 1) / BIN_CHUNK;
  const int gblocks = (N + 63) / 64;
  const int ablocks = (N + 15) / 16;      // 16 nodes per 256-thread block
  const int nprep = ((FIN * 64) >> 8) + ((HID * 64) >> 8) + 1;

  // init cursors + zero DEN
  hipLaunchKernelGGL(k_curinit, dim3((N + 255) / 256), dim3(256), 0, stream,
                     cursor, NB, DEN, N);
  // weight prep (one merged launch)
  hipLaunchKernelGGL(k_prep, dim3(nprep), dim3(256), 0, stream,
                     W1, W2, a2s, a2d, FIN, HID, NC,
                     whi1, wlo1, whi2, wlo2, w2s, w2d);
  // layer-1 GEMM: h1b(bf16) = x@W1 + scores S,D (needed by k_bin)
  hipLaunchKernelGGL(k_gemm_mfma, dim3(gblocks), dim3(256), 0, stream,
                     x, FIN, whi1, wlo1, a1s, a1d, HID, (float*)nullptr, h1b, 64, S, D, N);
  // CSR build with fused layer-1 edge coefficients (in the occupancy-rich k_bin)
  hipLaunchKernelGGL(k_bin, dim3(ebins), dim3(256), 0, stream,
                     ei, ew, E, N, S, D, cursor, staged, stagedEx, DEN, NB);
  hipLaunchKernelGGL(k_bscan, dim3(1), dim3(512), 0, stream, cursor, NB, NT, N, bbase, rp);
  hipLaunchKernelGGL(k_finalize, dim3(NB), dim3(512), 0, stream,
                     staged, stagedEx, bbase, N, rp, csrA, csrB);

  // ---- agg1 (pure gather-FMA): h1b -> h2b(bf16, ReLU) + layer-2 scores S2,D2 ----
  hipLaunchKernelGGL((k_agg<true, true, true, true>), dim3(ablocks), dim3(256), 0, stream,
                     rp, csrA, (const float*)nullptr, (const float*)nullptr, DEN,
                     h1b, (void*)h2b, w2s, w2d, S2, D2, N);
  // ---- agg2 (in-loop softmax): h2b -> A(f32, 64 cols); W2 commuted past the sum ----
  hipLaunchKernelGGL((k_agg<false, false, false, false>), dim3(ablocks), dim3(256), 0, stream,
                     rp, csrB, S2, D2, (const float*)nullptr,
                     h2b, (void*)A, (const float*)nullptr, (const float*)nullptr,
                     (float*)nullptr, (float*)nullptr, N);
  // ---- out = A @ W2 (dense MFMA, K=64; S/D scratch writes ignored) ----
  hipLaunchKernelGGL(k_gemm_mfma, dim3(gblocks), dim3(256), 0, stream,
                     A, HID, whi2, wlo2, a2s, a2d, NC, out, (unsigned short*)nullptr, NC, S, D, N);
}

// Round 8
// 371.562 us; speedup vs baseline: 1.2184x; 1.2184x over previous
//
#include <hip/hip_runtime.h>
#include <hip/hip_bf16.h>
#include <math.h>

#define NEG_SLOPE 0.2f

typedef __attribute__((ext_vector_type(4))) float f32x4;
typedef __attribute__((ext_vector_type(8))) short bf16x8;
typedef __attribute__((ext_vector_type(4))) short bf16x4;

__device__ __forceinline__ float leaky(float x) { return x > 0.f ? x : NEG_SLOPE * x; }

__device__ __forceinline__ unsigned short bf_hi(float x) {
  return (unsigned short)(__float_as_uint(x) >> 16);  // truncation split (exact residual)
}

__device__ __forceinline__ unsigned short bf_rne(float x) {
  unsigned u = __float_as_uint(x);
  return (unsigned short)((u + 0x7FFFu + ((u >> 16) & 1u)) >> 16);  // round-nearest-even
}

// ---------------- CSR build: bucket-local, fixed-capacity staging ----------------

#define BIN_CHUNK 2048
#define BCAP 8192

__global__ void k_curinit(int* __restrict__ cursor, int NB) {
  int i = blockIdx.x * blockDim.x + threadIdx.x;
  if (i < NB) cursor[i] = i * BCAP;
}

// stage edges bucket-contiguously; entry = (src | dstlow<<24, weight_bits)
__global__ __launch_bounds__(256)
void k_bin(const int* __restrict__ ei, const float* __restrict__ ew, int E, int N,
           int* __restrict__ cursor, int2* __restrict__ staged, int NB) {
  __shared__ int lhist[512];
  __shared__ int lbase[512];
  int tid = threadIdx.x;
  int start = blockIdx.x * BIN_CHUNK;
  int NT = E + N;
  int srcv[8], dstv[8]; float wv[8];
#pragma unroll
  for (int j = 0; j < 8; j++) {
    int e = start + j * 256 + tid;       // coalesced
    int s = 0, d = -1; float w = 0.f;
    if (e < NT) {
      if (e < E) { s = ei[e]; d = ei[E + e]; w = ew[e]; }
      else       { s = d = e - E; w = 1.f; }   // self-loop
    }
    srcv[j] = s; dstv[j] = d; wv[j] = w;
  }
  for (int b = tid; b < NB; b += 256) lhist[b] = 0;
  __syncthreads();
#pragma unroll
  for (int j = 0; j < 8; j++)
    if (dstv[j] >= 0) atomicAdd(&lhist[dstv[j] >> 8], 1);
  __syncthreads();
  for (int b = tid; b < NB; b += 256) {
    int n = lhist[b];
    lbase[b] = (n > 0) ? atomicAdd(&cursor[b], n) : 0;
    lhist[b] = 0;
  }
  __syncthreads();
#pragma unroll
  for (int j = 0; j < 8; j++) {
    if (dstv[j] >= 0) {
      int bkt = dstv[j] >> 8;
      int off = atomicAdd(&lhist[bkt], 1);          // LDS cursor
      staged[lbase[bkt] + off] =
          make_int2(srcv[j] | ((dstv[j] & 255) << 24), __float_as_int(wv[j]));
    }
  }
}

// totals from cursor deltas -> parallel exclusive scan -> packed bases
__global__ __launch_bounds__(512)
void k_bscan(const int* __restrict__ cursor, int NB, int NT, int N,
             int* __restrict__ bbase, int* __restrict__ rp) {
  __shared__ int sm[512];
  int tid = threadIdx.x;                           // 512 threads, NB <= 512
  int v = (tid < NB) ? cursor[tid] - tid * BCAP : 0;
  sm[tid] = v;
  __syncthreads();
  for (int off = 1; off < 512; off <<= 1) {        // Hillis-Steele inclusive
    int x = sm[tid];
    int a = (tid >= off) ? sm[tid - off] : 0;
    __syncthreads();
    sm[tid] = x + a;
    __syncthreads();
  }
  if (tid < NB) bbase[tid] = sm[tid] - v;          // exclusive
  if (tid == 0) { bbase[NB] = sm[NB - 1]; rp[N] = NT; }
}

// one block per bucket: LDS count -> scan -> rp -> LDS-cursor scatter to packed csr
__global__ __launch_bounds__(512)
void k_finalize(const int2* __restrict__ staged, const int* __restrict__ bbase,
                int N, int* __restrict__ rp, int2* __restrict__ csr) {
  __shared__ int cnt[256];
  __shared__ int sm[256];
  int b = blockIdx.x, tid = threadIdx.x;
  int sbase = b * BCAP;
  int cbase = bbase[b];
  int size = bbase[b + 1] - cbase;
  if (tid < 256) cnt[tid] = 0;
  __syncthreads();
  for (int i = tid; i < size; i += 512) {
    int2 v = staged[sbase + i];
    atomicAdd(&cnt[((unsigned)v.x) >> 24], 1);
  }
  __syncthreads();
  int s = 0;
  if (tid < 256) { s = cnt[tid]; sm[tid] = s; }
  __syncthreads();
  for (int off = 1; off < 256; off <<= 1) {        // Hillis-Steele inclusive scan
    int x = 0;
    if (tid < 256) { x = sm[tid]; if (tid >= off) x += sm[tid - off]; }
    __syncthreads();
    if (tid < 256) sm[tid] = x;
    __syncthreads();
  }
  if (tid < 256) {
    int excl = sm[tid] - s;
    int node = (b << 8) + tid;
    if (node < N) rp[node] = cbase + excl;
    cnt[tid] = excl;                               // becomes the scatter cursor
  }
  __syncthreads();
  for (int i = tid; i < size; i += 512) {
    int2 v = staged[sbase + i];
    int dlow = ((unsigned)v.x) >> 24;
    int pos = cbase + atomicAdd(&cnt[dlow], 1);    // LDS atomic
    csr[pos] = make_int2(v.x & 0x00FFFFFF, v.y);
  }
}

// ---------------- W pre-conversion to fragment-linear bf16 hi/lo images ----------------
__global__ __launch_bounds__(256)
void k_wprep(const float* __restrict__ W, int K, int Mout,
             unsigned short* __restrict__ whi, unsigned short* __restrict__ wlo) {
  int idx = blockIdx.x * 256 + threadIdx.x;    // k*64 + n
  if (idx >= K * 64) return;
  int k = idx >> 6, n = idx & 63;
  float v = (n < Mout) ? W[(size_t)k * Mout + n] : 0.f;
  unsigned short h = bf_hi(v);
  float hf = __uint_as_float((unsigned)h << 16);
  unsigned short l = bf_hi(v - hf);
  int kc = k >> 5, kk = k & 31, quad = kk >> 3, j = kk & 7;
  int ct = n >> 4, nn = n & 15;
  int off = (((kc * 4 + ct) * 64) + quad * 16 + nn) * 8 + j;
  whi[off] = h; wlo[off] = l;
}

// w2s = W2 @ a2_src, w2d = W2 @ a2_dst  (64-dim each; lets layer-2 scores be
// computed as h2 . w2s without materializing h2@W2)
__global__ void k_wvec(const float* __restrict__ W2, const float* __restrict__ a2s,
                       const float* __restrict__ a2d, int K, int NC,
                       float* __restrict__ ws, float* __restrict__ wd) {
  int k = threadIdx.x;
  if (k >= K) return;
  float s = 0.f, d = 0.f;
  for (int n = 0; n < NC; n++) {
    float w = W2[(size_t)k * NC + n];
    s += w * a2s[n]; d += w * a2d[n];
  }
  ws[k] = s; wd[k] = d;
}

// ---------------- MFMA GEMM (split-bf16) + fused attention scores ----------------
// Writes H either f32 (Hf) or RNE bf16 (Hb), row stride ldH, cols < Mout only.
__global__ __launch_bounds__(256)
void k_gemm_mfma(const float* __restrict__ X, int K,
                 const unsigned short* __restrict__ WHI, const unsigned short* __restrict__ WLO,
                 const float* __restrict__ ASRC, const float* __restrict__ ADST, int Mout,
                 float* __restrict__ Hf, unsigned short* __restrict__ Hb, int ldH,
                 float* __restrict__ S, float* __restrict__ D, int N) {
  __shared__ __align__(16) unsigned short xhi[2048], xlo[2048];   // 4 rowtiles*64 lanes*8
  __shared__ __align__(16) unsigned short whs[2048], wls[2048];   // 4 coltiles*64 lanes*8
  int tid = threadIdx.x;
  int lane = tid & 63, w = tid >> 6;
  int rowBase = blockIdx.x * 64;

  f32x4 acc[4];
#pragma unroll
  for (int c = 0; c < 4; c++) acc[c] = (f32x4){0.f, 0.f, 0.f, 0.f};

  int q0 = tid, q1 = tid + 256;
  int row0 = q0 >> 3, k40 = (q0 & 7) << 2;
  int row1 = q1 >> 3, k41 = (q1 & 7) << 2;
  int xo0 = (((row0 >> 4) * 64) + (k40 >> 3) * 16 + (row0 & 15)) * 8 + (k40 & 7);
  int xo1 = (((row1 >> 4) * 64) + (k41 >> 3) * 16 + (row1 & 15)) * 8 + (k41 & 7);
  int grow0 = rowBase + row0, grow1 = rowBase + row1;

  int nch = K >> 5;
  f32x4 xr0, xr1; bf16x8 wh, wl;

  xr0 = (f32x4){0.f, 0.f, 0.f, 0.f}; xr1 = xr0;
  if (grow0 < N) xr0 = *(const f32x4*)&X[(size_t)grow0 * K + k40];
  if (grow1 < N) xr1 = *(const f32x4*)&X[(size_t)grow1 * K + k41];
  wh = *(const bf16x8*)(WHI + tid * 8);
  wl = *(const bf16x8*)(WLO + tid * 8);

  for (int kc = 0; kc < nch; kc++) {
    bf16x4 h4, l4;
#pragma unroll
    for (int i = 0; i < 4; i++) {
      unsigned short h = bf_hi(xr0[i]);
      float hf = __uint_as_float((unsigned)h << 16);
      h4[i] = (short)h; l4[i] = (short)bf_hi(xr0[i] - hf);
    }
    *(bf16x4*)(xhi + xo0) = h4; *(bf16x4*)(xlo + xo0) = l4;
#pragma unroll
    for (int i = 0; i < 4; i++) {
      unsigned short h = bf_hi(xr1[i]);
      float hf = __uint_as_float((unsigned)h << 16);
      h4[i] = (short)h; l4[i] = (short)bf_hi(xr1[i] - hf);
    }
    *(bf16x4*)(xhi + xo1) = h4; *(bf16x4*)(xlo + xo1) = l4;
    *(bf16x8*)(whs + tid * 8) = wh;
    *(bf16x8*)(wls + tid * 8) = wl;
    __syncthreads();

    if (kc + 1 < nch) {
      int kb = (kc + 1) << 5;
      xr0 = (f32x4){0.f, 0.f, 0.f, 0.f}; xr1 = xr0;
      if (grow0 < N) xr0 = *(const f32x4*)&X[(size_t)grow0 * K + kb + k40];
      if (grow1 < N) xr1 = *(const f32x4*)&X[(size_t)grow1 * K + kb + k41];
      wh = *(const bf16x8*)(WHI + (size_t)(kc + 1) * 2048 + tid * 8);
      wl = *(const bf16x8*)(WLO + (size_t)(kc + 1) * 2048 + tid * 8);
    }

    bf16x8 ah = *(const bf16x8*)(xhi + (w * 64 + lane) * 8);
    bf16x8 al = *(const bf16x8*)(xlo + (w * 64 + lane) * 8);
#pragma unroll
    for (int c = 0; c < 4; c++) {
      bf16x8 bh = *(const bf16x8*)(whs + (c * 64 + lane) * 8);
      bf16x8 bl = *(const bf16x8*)(wls + (c * 64 + lane) * 8);
      acc[c] = __builtin_amdgcn_mfma_f32_16x16x32_bf16(ah, bh, acc[c], 0, 0, 0);
      acc[c] = __builtin_amdgcn_mfma_f32_16x16x32_bf16(ah, bl, acc[c], 0, 0, 0);
      acc[c] = __builtin_amdgcn_mfma_f32_16x16x32_bf16(al, bh, acc[c], 0, 0, 0);
    }
    __syncthreads();
  }

  int nn = lane & 15, quad = lane >> 4;
  float as_[4], ad_[4];
#pragma unroll
  for (int c = 0; c < 4; c++) {
    int col = c * 16 + nn;
    as_[c] = (col < Mout) ? ASRC[col] : 0.f;
    ad_[c] = (col < Mout) ? ADST[col] : 0.f;
  }
#pragma unroll
  for (int r = 0; r < 4; r++) {
    int grow = rowBase + w * 16 + quad * 4 + r;
    float ps = 0.f, pd = 0.f;
#pragma unroll
    for (int c = 0; c < 4; c++) {
      float v = acc[c][r];
      int col = c * 16 + nn;
      if (grow < N && col < Mout) {
        if (Hb) Hb[(size_t)grow * ldH + col] = bf_rne(v);
        else    Hf[(size_t)grow * ldH + col] = v;
      }
      ps += v * as_[c]; pd += v * ad_[c];
    }
#pragma unroll
    for (int off = 1; off < 16; off <<= 1) {
      ps += __shfl_xor(ps, off);
      pd += __shfl_xor(pd, off);
    }
    if (nn == 0 && grow < N) { S[grow] = ps; D[grow] = pd; }
  }
}

// ---------------- fused aggregation: no-max softmax, branch-free, 8 deep -------------
// 4 nodes per wave, 16 lanes each, 64 bf16 cols per row (1 cache line per edge).
// R4 structure with gather depth 4 -> 8: all 8 H-row gathers + 8 S gathers per
// iteration are unconditional, mutually independent, clamped-safe (no exec-mask
// regions, no branches). csr meta for window t+8 prefetched while t computes.
// Four accumulator chains keep the FMA dependency short. Masking on values only.
template <bool OUTB16, bool RELU, bool SCORES>
__global__ __launch_bounds__(256)
void k_agg(const int* __restrict__ rp, const int2* __restrict__ csr,
           const float* __restrict__ Sc, const float* __restrict__ Dc,
           const unsigned short* __restrict__ Hb, void* __restrict__ OutV,
           const float* __restrict__ WS, const float* __restrict__ WD,
           float* __restrict__ S2, float* __restrict__ D2, int N) {
  int gw = (blockIdx.x * blockDim.x + threadIdx.x) >> 6;
  int lane = threadIdx.x & 63;
  int sub = lane >> 4, fl = lane & 15;
  int node = gw * 4 + sub;
  bool active = node < N;
  int b = 0, e = 1; float dd = 0.f;
  if (active) { b = rp[node]; e = rp[node + 1]; dd = Dc[node]; }
  float den = 0.f;
  f32x4 acc0 = (f32x4){0.f, 0.f, 0.f, 0.f};
  f32x4 acc1 = (f32x4){0.f, 0.f, 0.f, 0.f};
  f32x4 acc2 = (f32x4){0.f, 0.f, 0.f, 0.f};
  f32x4 acc3 = (f32x4){0.f, 0.f, 0.f, 0.f};

  int need = e - b;
  need = max(need, __shfl_xor(need, 16));
  need = max(need, __shfl_xor(need, 32));
  int iters = (need + 7) >> 3;
  int last = e - 1;

  // preload window-0 meta
  int idx[8]; float wgt[8];
  int t = b;
#pragma unroll
  for (int j = 0; j < 8; j++) {
    int tj = (t + j < e) ? t + j : last;            // clamped-safe, warm line
    int2 p = csr[tj];
    idx[j] = p.x;
    wgt[j] = (t + j < e) ? __int_as_float(p.y) : 0.f;
  }

  for (int it = 0; it < iters; it++, t += 8) {
    // scores for current window (S table 400KB -> L2-hot)
    float sv[8];
#pragma unroll
    for (int j = 0; j < 8; j++) sv[j] = Sc[idx[j]];
    // H row gathers: unconditional, 8B/lane, 128B/row, 8 independent lines in flight
    ushort4 uv[8];
#pragma unroll
    for (int j = 0; j < 8; j++)
      uv[j] = *(const ushort4*)(Hb + (size_t)idx[j] * 64 + (fl << 2));
    // prefetch next window's csr meta (clamped-safe; dummy on last iter)
    int idn[8]; float wgn[8];
#pragma unroll
    for (int j = 0; j < 8; j++) {
      int tj = (t + 8 + j < e) ? t + 8 + j : last;
      int2 p = csr[tj];
      idn[j] = p.x;
      wgn[j] = (t + 8 + j < e) ? __int_as_float(p.y) : 0.f;
    }
    // compute current window
    float ex[8];
#pragma unroll
    for (int j = 0; j < 8; j++)
      ex[j] = (t + j < e) ? __expf(leaky(sv[j] + dd)) : 0.f;
    den += ((ex[0] + ex[1]) + (ex[2] + ex[3])) + ((ex[4] + ex[5]) + (ex[6] + ex[7]));
    f32x4 hv[8];
#pragma unroll
    for (int j = 0; j < 8; j++) {
      hv[j][0] = __uint_as_float((unsigned)uv[j].x << 16);
      hv[j][1] = __uint_as_float((unsigned)uv[j].y << 16);
      hv[j][2] = __uint_as_float((unsigned)uv[j].z << 16);
      hv[j][3] = __uint_as_float((unsigned)uv[j].w << 16);
    }
    acc0 += hv[0] * (ex[0] * wgt[0]) + hv[1] * (ex[1] * wgt[1]);
    acc1 += hv[2] * (ex[2] * wgt[2]) + hv[3] * (ex[3] * wgt[3]);
    acc2 += hv[4] * (ex[4] * wgt[4]) + hv[5] * (ex[5] * wgt[5]);
    acc3 += hv[6] * (ex[6] * wgt[6]) + hv[7] * (ex[7] * wgt[7]);
    // rotate meta
#pragma unroll
    for (int j = 0; j < 8; j++) { idx[j] = idn[j]; wgt[j] = wgn[j]; }
  }

  float inv = 1.0f / fmaxf(den, 1e-16f);
  f32x4 o = ((acc0 + acc1) + (acc2 + acc3)) * inv;
  if (RELU) {
#pragma unroll
    for (int j = 0; j < 4; j++) o[j] = fmaxf(o[j], 0.f);
  }
  if (SCORES) {                                    // layer-2 scores from f32 values
    f32x4 ws = *(const f32x4*)&WS[fl << 2];
    f32x4 wd = *(const f32x4*)&WD[fl << 2];
    float ps = o[0] * ws[0] + o[1] * ws[1] + o[2] * ws[2] + o[3] * ws[3];
    float pd = o[0] * wd[0] + o[1] * wd[1] + o[2] * wd[2] + o[3] * wd[3];
#pragma unroll
    for (int off = 1; off < 16; off <<= 1) {
      ps += __shfl_xor(ps, off);
      pd += __shfl_xor(pd, off);
    }
    if (active && fl == 0) { S2[node] = ps; D2[node] = pd; }
  }
  if (active) {
    if (OUTB16) {
      ushort4 st;
      st.x = bf_rne(o[0]); st.y = bf_rne(o[1]); st.z = bf_rne(o[2]); st.w = bf_rne(o[3]);
      *(ushort4*)((unsigned short*)OutV + (size_t)node * 64 + (fl << 2)) = st;
    } else {
      *(f32x4*)((float*)OutV + (size_t)node * 64 + (fl << 2)) = o;
    }
  }
}

// ---------------- launch ----------------
extern "C" void kernel_launch(void* const* d_in, const int* in_sizes, int n_in,
                              void* d_out, int out_size, void* d_ws, size_t ws_size,
                              hipStream_t stream) {
  const float* x   = (const float*)d_in[0];
  const int*   ei  = (const int*)d_in[1];
  const float* ew  = (const float*)d_in[2];
  const float* W1  = (const float*)d_in[3];
  const float* a1s = (const float*)d_in[4];
  const float* a1d = (const float*)d_in[5];
  const float* W2  = (const float*)d_in[6];
  const float* a2s = (const float*)d_in[7];
  const float* a2d = (const float*)d_in[8];

  const int HID = in_sizes[4];            // 64
  const int NC  = in_sizes[7];            // 40
  const int FIN = in_sizes[3] / HID;      // 256
  const int N   = in_sizes[0] / FIN;      // 100000
  const int E   = in_sizes[2];            // 1600000
  const int NT  = E + N;
  const int NB  = (N + 255) >> 8;         // 391 buckets
  float* out = (float*)d_out;

  char* wsb = (char*)d_ws;
  size_t off = 0;
  auto alloc = [&](size_t bytes) -> char* {
    char* p = wsb + off;
    off += (bytes + 255) & ~(size_t)255;
    return p;
  };
  unsigned short* h1b = (unsigned short*)alloc((size_t)N * 64 * 2);  // layer-1 bf16 image
  unsigned short* h2b = (unsigned short*)alloc((size_t)N * 64 * 2);  // layer-2 bf16 image
  float* A      = (float*)alloc((size_t)N * 64 * 4);   // layer-2 aggregated (pre-W2)
  float* S      = (float*)alloc((size_t)N * 4);
  float* D      = (float*)alloc((size_t)N * 4);
  float* S2     = (float*)alloc((size_t)N * 4);
  float* D2     = (float*)alloc((size_t)N * 4);
  int*   rp     = (int*)alloc((size_t)(N + 1) * 4);
  int*   bbase  = (int*)alloc((size_t)(NB + 1) * 4);
  int*   cursor = (int*)alloc((size_t)NB * 4);
  int2*  csr    = (int2*)alloc((size_t)NT * 8);
  int2*  staged = (int2*)alloc((size_t)NB * BCAP * 8);
  unsigned short* whi1 = (unsigned short*)alloc((size_t)FIN * 64 * 2);
  unsigned short* wlo1 = (unsigned short*)alloc((size_t)FIN * 64 * 2);
  unsigned short* whi2 = (unsigned short*)alloc((size_t)HID * 64 * 2);
  unsigned short* wlo2 = (unsigned short*)alloc((size_t)HID * 64 * 2);
  float* w2s = (float*)alloc((size_t)HID * 4);
  float* w2d = (float*)alloc((size_t)HID * 4);
  (void)ws_size; (void)n_in; (void)out_size;

  const int ebins = (NT + BIN_CHUNK - 1) / BIN_CHUNK;

  hipLaunchKernelGGL(k_curinit, dim3((NB + 255) / 256), dim3(256), 0, stream, cursor, NB);
  hipLaunchKernelGGL(k_bin, dim3(ebins), dim3(256), 0, stream, ei, ew, E, N, cursor, staged, NB);
  hipLaunchKernelGGL(k_bscan, dim3(1), dim3(512), 0, stream, cursor, NB, NT, N, bbase, rp);
  hipLaunchKernelGGL(k_finalize, dim3(NB), dim3(512), 0, stream, staged, bbase, N, rp, csr);

  hipLaunchKernelGGL(k_wprep, dim3((FIN * 64 + 255) / 256), dim3(256), 0, stream,
                     W1, FIN, HID, whi1, wlo1);
  hipLaunchKernelGGL(k_wprep, dim3((HID * 64 + 255) / 256), dim3(256), 0, stream,
                     W2, HID, NC, whi2, wlo2);
  hipLaunchKernelGGL(k_wvec, dim3(1), dim3(64), 0, stream, W2, a2s, a2d, HID, NC, w2s, w2d);

  const int gblocks = (N + 63) / 64;
  const int ablocks = (N + 15) / 16;      // 16 nodes per 256-thread block

  // ---- layer 1: h1b(bf16) = x@W1 + scores S,D ----
  hipLaunchKernelGGL(k_gemm_mfma, dim3(gblocks), dim3(256), 0, stream,
                     x, FIN, whi1, wlo1, a1s, a1d, HID, (float*)nullptr, h1b, 64, S, D, N);
  // ---- agg1: softmax-aggregate h1b -> h2b(bf16, ReLU); fused layer-2 scores S2,D2 ----
  hipLaunchKernelGGL((k_agg<true, true, true>), dim3(ablocks), dim3(256), 0, stream,
                     rp, csr, S, D, h1b, (void*)h2b, w2s, w2d, S2, D2, N);
  // ---- agg2: softmax-aggregate h2b -> A(f32, 64 cols); W2 commuted past the sum ----
  hipLaunchKernelGGL((k_agg<false, false, false>), dim3(ablocks), dim3(256), 0, stream,
                     rp, csr, S2, D2, h2b, (void*)A, (const float*)nullptr,
                     (const float*)nullptr, (float*)nullptr, (float*)nullptr, N);
  // ---- out = A @ W2 (dense MFMA, K=64; S/D scratch writes ignored) ----
  hipLaunchKernelGGL(k_gemm_mfma, dim3(gblocks), dim3(256), 0, stream,
                     A, HID, whi2, wlo2, a2s, a2d, NC, out, (unsigned short*)nullptr, NC, S, D, N);
}

// Round 9
// 353.866 us; speedup vs baseline: 1.2793x; 1.0500x over previous
//
#include <hip/hip_runtime.h>
#include <hip/hip_bf16.h>
#include <math.h>

#define NEG_SLOPE 0.2f

typedef __attribute__((ext_vector_type(4))) float f32x4;
typedef __attribute__((ext_vector_type(8))) short bf16x8;
typedef __attribute__((ext_vector_type(4))) short bf16x4;

__device__ __forceinline__ float leaky(float x) { return x > 0.f ? x : NEG_SLOPE * x; }

__device__ __forceinline__ unsigned short bf_hi(float x) {
  return (unsigned short)(__float_as_uint(x) >> 16);  // truncation split (exact residual)
}

__device__ __forceinline__ unsigned short bf_rne(float x) {
  unsigned u = __float_as_uint(x);
  return (unsigned short)((u + 0x7FFFu + ((u >> 16) & 1u)) >> 16);  // round-nearest-even
}

// ---------------- CSR build: bucket-local, fixed-capacity staging ----------------

#define BIN_CHUNK 2048
#define BCAP 8192

__global__ void k_curinit(int* __restrict__ cursor, int NB) {
  int i = blockIdx.x * blockDim.x + threadIdx.x;
  if (i < NB) cursor[i] = i * BCAP;
}

// stage edges bucket-contiguously; entry = (src | dstlow<<24, weight_bits)
__global__ __launch_bounds__(256)
void k_bin(const int* __restrict__ ei, const float* __restrict__ ew, int E, int N,
           int* __restrict__ cursor, int2* __restrict__ staged, int NB) {
  __shared__ int lhist[512];
  __shared__ int lbase[512];
  int tid = threadIdx.x;
  int start = blockIdx.x * BIN_CHUNK;
  int NT = E + N;
  int srcv[8], dstv[8]; float wv[8];
#pragma unroll
  for (int j = 0; j < 8; j++) {
    int e = start + j * 256 + tid;       // coalesced
    int s = 0, d = -1; float w = 0.f;
    if (e < NT) {
      if (e < E) { s = ei[e]; d = ei[E + e]; w = ew[e]; }
      else       { s = d = e - E; w = 1.f; }   // self-loop
    }
    srcv[j] = s; dstv[j] = d; wv[j] = w;
  }
  for (int b = tid; b < NB; b += 256) lhist[b] = 0;
  __syncthreads();
#pragma unroll
  for (int j = 0; j < 8; j++)
    if (dstv[j] >= 0) atomicAdd(&lhist[dstv[j] >> 8], 1);
  __syncthreads();
  for (int b = tid; b < NB; b += 256) {
    int n = lhist[b];
    lbase[b] = (n > 0) ? atomicAdd(&cursor[b], n) : 0;
    lhist[b] = 0;
  }
  __syncthreads();
#pragma unroll
  for (int j = 0; j < 8; j++) {
    if (dstv[j] >= 0) {
      int bkt = dstv[j] >> 8;
      int off = atomicAdd(&lhist[bkt], 1);          // LDS cursor
      staged[lbase[bkt] + off] =
          make_int2(srcv[j] | ((dstv[j] & 255) << 24), __float_as_int(wv[j]));
    }
  }
}

// totals from cursor deltas -> parallel exclusive scan -> packed bases
__global__ __launch_bounds__(512)
void k_bscan(const int* __restrict__ cursor, int NB, int NT, int N,
             int* __restrict__ bbase, int* __restrict__ rp) {
  __shared__ int sm[512];
  int tid = threadIdx.x;                           // 512 threads, NB <= 512
  int v = (tid < NB) ? cursor[tid] - tid * BCAP : 0;
  sm[tid] = v;
  __syncthreads();
  for (int off = 1; off < 512; off <<= 1) {        // Hillis-Steele inclusive
    int x = sm[tid];
    int a = (tid >= off) ? sm[tid - off] : 0;
    __syncthreads();
    sm[tid] = x + a;
    __syncthreads();
  }
  if (tid < NB) bbase[tid] = sm[tid] - v;          // exclusive
  if (tid == 0) { bbase[NB] = sm[NB - 1]; rp[N] = NT; }
}

// one block per bucket: LDS count -> scan -> rp -> LDS-cursor scatter to packed csr
__global__ __launch_bounds__(512)
void k_finalize(const int2* __restrict__ staged, const int* __restrict__ bbase,
                int N, int* __restrict__ rp, int2* __restrict__ csr) {
  __shared__ int cnt[256];
  __shared__ int sm[256];
  int b = blockIdx.x, tid = threadIdx.x;
  int sbase = b * BCAP;
  int cbase = bbase[b];
  int size = bbase[b + 1] - cbase;
  if (tid < 256) cnt[tid] = 0;
  __syncthreads();
  for (int i = tid; i < size; i += 512) {
    int2 v = staged[sbase + i];
    atomicAdd(&cnt[((unsigned)v.x) >> 24], 1);
  }
  __syncthreads();
  int s = 0;
  if (tid < 256) { s = cnt[tid]; sm[tid] = s; }
  __syncthreads();
  for (int off = 1; off < 256; off <<= 1) {        // Hillis-Steele inclusive scan
    int x = 0;
    if (tid < 256) { x = sm[tid]; if (tid >= off) x += sm[tid - off]; }
    __syncthreads();
    if (tid < 256) sm[tid] = x;
    __syncthreads();
  }
  if (tid < 256) {
    int excl = sm[tid] - s;
    int node = (b << 8) + tid;
    if (node < N) rp[node] = cbase + excl;
    cnt[tid] = excl;                               // becomes the scatter cursor
  }
  __syncthreads();
  for (int i = tid; i < size; i += 512) {
    int2 v = staged[sbase + i];
    int dlow = ((unsigned)v.x) >> 24;
    int pos = cbase + atomicAdd(&cnt[dlow], 1);    // LDS atomic
    csr[pos] = make_int2(v.x & 0x00FFFFFF, v.y);
  }
}

// ---------------- merged weight prep: W1/W2 bf16 hi/lo images + w2s/w2d vectors ------
// (verified innocuous in R6: identical absmax; R6's regression was k_bin's atomics)
__device__ __forceinline__ void wprep_one(const float* __restrict__ W, int idx, int Mout,
                                          unsigned short* __restrict__ whi,
                                          unsigned short* __restrict__ wlo) {
  int k = idx >> 6, n = idx & 63;
  float v = (n < Mout) ? W[(size_t)k * Mout + n] : 0.f;
  unsigned short h = bf_hi(v);
  float hf = __uint_as_float((unsigned)h << 16);
  unsigned short l = bf_hi(v - hf);
  int kc = k >> 5, kk = k & 31, quad = kk >> 3, j = kk & 7;
  int ct = n >> 4, nn = n & 15;
  int off = (((kc * 4 + ct) * 64) + quad * 16 + nn) * 8 + j;
  whi[off] = h; wlo[off] = l;
}

__global__ __launch_bounds__(256)
void k_prep(const float* __restrict__ W1, const float* __restrict__ W2,
            const float* __restrict__ a2s, const float* __restrict__ a2d,
            int FIN, int HID, int NC,
            unsigned short* __restrict__ whi1, unsigned short* __restrict__ wlo1,
            unsigned short* __restrict__ whi2, unsigned short* __restrict__ wlo2,
            float* __restrict__ w2s, float* __restrict__ w2d) {
  int blk = blockIdx.x, tid = threadIdx.x;
  int nb1 = (FIN * 64) >> 8;                       // 64 blocks for W1
  int nb2 = (HID * 64) >> 8;                       // 16 blocks for W2
  if (blk < nb1) {
    wprep_one(W1, blk * 256 + tid, HID, whi1, wlo1);
  } else if (blk < nb1 + nb2) {
    wprep_one(W2, (blk - nb1) * 256 + tid, NC, whi2, wlo2);
  } else {
    if (tid < HID) {                               // w2s = W2@a2s, w2d = W2@a2d
      float s = 0.f, d = 0.f;
      for (int n = 0; n < NC; n++) {
        float w = W2[(size_t)tid * NC + n];
        s += w * a2s[n]; d += w * a2d[n];
      }
      w2s[tid] = s; w2d[tid] = d;
    }
  }
}

// ---------------- MFMA GEMM (split-bf16) + fused attention scores ----------------
// Writes H either f32 (Hf) or RNE bf16 (Hb), row stride ldH, cols < Mout only.
__global__ __launch_bounds__(256)
void k_gemm_mfma(const float* __restrict__ X, int K,
                 const unsigned short* __restrict__ WHI, const unsigned short* __restrict__ WLO,
                 const float* __restrict__ ASRC, const float* __restrict__ ADST, int Mout,
                 float* __restrict__ Hf, unsigned short* __restrict__ Hb, int ldH,
                 float* __restrict__ S, float* __restrict__ D, int N) {
  __shared__ __align__(16) unsigned short xhi[2048], xlo[2048];   // 4 rowtiles*64 lanes*8
  __shared__ __align__(16) unsigned short whs[2048], wls[2048];   // 4 coltiles*64 lanes*8
  int tid = threadIdx.x;
  int lane = tid & 63, w = tid >> 6;
  int rowBase = blockIdx.x * 64;

  f32x4 acc[4];
#pragma unroll
  for (int c = 0; c < 4; c++) acc[c] = (f32x4){0.f, 0.f, 0.f, 0.f};

  int q0 = tid, q1 = tid + 256;
  int row0 = q0 >> 3, k40 = (q0 & 7) << 2;
  int row1 = q1 >> 3, k41 = (q1 & 7) << 2;
  int xo0 = (((row0 >> 4) * 64) + (k40 >> 3) * 16 + (row0 & 15)) * 8 + (k40 & 7);
  int xo1 = (((row1 >> 4) * 64) + (k41 >> 3) * 16 + (row1 & 15)) * 8 + (k41 & 7);
  int grow0 = rowBase + row0, grow1 = rowBase + row1;

  int nch = K >> 5;
  f32x4 xr0, xr1; bf16x8 wh, wl;

  xr0 = (f32x4){0.f, 0.f, 0.f, 0.f}; xr1 = xr0;
  if (grow0 < N) xr0 = *(const f32x4*)&X[(size_t)grow0 * K + k40];
  if (grow1 < N) xr1 = *(const f32x4*)&X[(size_t)grow1 * K + k41];
  wh = *(const bf16x8*)(WHI + tid * 8);
  wl = *(const bf16x8*)(WLO + tid * 8);

  for (int kc = 0; kc < nch; kc++) {
    bf16x4 h4, l4;
#pragma unroll
    for (int i = 0; i < 4; i++) {
      unsigned short h = bf_hi(xr0[i]);
      float hf = __uint_as_float((unsigned)h << 16);
      h4[i] = (short)h; l4[i] = (short)bf_hi(xr0[i] - hf);
    }
    *(bf16x4*)(xhi + xo0) = h4; *(bf16x4*)(xlo + xo0) = l4;
#pragma unroll
    for (int i = 0; i < 4; i++) {
      unsigned short h = bf_hi(xr1[i]);
      float hf = __uint_as_float((unsigned)h << 16);
      h4[i] = (short)h; l4[i] = (short)bf_hi(xr1[i] - hf);
    }
    *(bf16x4*)(xhi + xo1) = h4; *(bf16x4*)(xlo + xo1) = l4;
    *(bf16x8*)(whs + tid * 8) = wh;
    *(bf16x8*)(wls + tid * 8) = wl;
    __syncthreads();

    if (kc + 1 < nch) {
      int kb = (kc + 1) << 5;
      xr0 = (f32x4){0.f, 0.f, 0.f, 0.f}; xr1 = xr0;
      if (grow0 < N) xr0 = *(const f32x4*)&X[(size_t)grow0 * K + kb + k40];
      if (grow1 < N) xr1 = *(const f32x4*)&X[(size_t)grow1 * K + kb + k41];
      wh = *(const bf16x8*)(WHI + (size_t)(kc + 1) * 2048 + tid * 8);
      wl = *(const bf16x8*)(WLO + (size_t)(kc + 1) * 2048 + tid * 8);
    }

    bf16x8 ah = *(const bf16x8*)(xhi + (w * 64 + lane) * 8);
    bf16x8 al = *(const bf16x8*)(xlo + (w * 64 + lane) * 8);
#pragma unroll
    for (int c = 0; c < 4; c++) {
      bf16x8 bh = *(const bf16x8*)(whs + (c * 64 + lane) * 8);
      bf16x8 bl = *(const bf16x8*)(wls + (c * 64 + lane) * 8);
      acc[c] = __builtin_amdgcn_mfma_f32_16x16x32_bf16(ah, bh, acc[c], 0, 0, 0);
      acc[c] = __builtin_amdgcn_mfma_f32_16x16x32_bf16(ah, bl, acc[c], 0, 0, 0);
      acc[c] = __builtin_amdgcn_mfma_f32_16x16x32_bf16(al, bh, acc[c], 0, 0, 0);
    }
    __syncthreads();
  }

  int nn = lane & 15, quad = lane >> 4;
  float as_[4], ad_[4];
#pragma unroll
  for (int c = 0; c < 4; c++) {
    int col = c * 16 + nn;
    as_[c] = (col < Mout) ? ASRC[col] : 0.f;
    ad_[c] = (col < Mout) ? ADST[col] : 0.f;
  }
#pragma unroll
  for (int r = 0; r < 4; r++) {
    int grow = rowBase + w * 16 + quad * 4 + r;
    float ps = 0.f, pd = 0.f;
#pragma unroll
    for (int c = 0; c < 4; c++) {
      float v = acc[c][r];
      int col = c * 16 + nn;
      if (grow < N && col < Mout) {
        if (Hb) Hb[(size_t)grow * ldH + col] = bf_rne(v);
        else    Hf[(size_t)grow * ldH + col] = v;
      }
      ps += v * as_[c]; pd += v * ad_[c];
    }
#pragma unroll
    for (int off = 1; off < 16; off <<= 1) {
      ps += __shfl_xor(ps, off);
      pd += __shfl_xor(pd, off);
    }
    if (nn == 0 && grow < N) { S[grow] = ps; D[grow] = pd; }
  }
}

// ---------------- fused aggregation: no-max softmax, branch-free, pipelined ----------
// R4's measured-best shape: 4 nodes per wave, 16 lanes each, depth 4, csr meta
// prefetched one window ahead, all loads unconditional clamped-safe, masking on
// values only. (Depth 8 regressed twice: R2 branchy, R8 occupancy collapse.)
template <bool OUTB16, bool RELU, bool SCORES>
__global__ __launch_bounds__(256)
void k_agg(const int* __restrict__ rp, const int2* __restrict__ csr,
           const float* __restrict__ Sc, const float* __restrict__ Dc,
           const unsigned short* __restrict__ Hb, void* __restrict__ OutV,
           const float* __restrict__ WS, const float* __restrict__ WD,
           float* __restrict__ S2, float* __restrict__ D2, int N) {
  int gw = (blockIdx.x * blockDim.x + threadIdx.x) >> 6;
  int lane = threadIdx.x & 63;
  int sub = lane >> 4, fl = lane & 15;
  int node = gw * 4 + sub;
  bool active = node < N;
  int b = 0, e = 1; float dd = 0.f;
  if (active) { b = rp[node]; e = rp[node + 1]; dd = Dc[node]; }
  float den = 0.f;
  f32x4 acc0 = (f32x4){0.f, 0.f, 0.f, 0.f};
  f32x4 acc1 = (f32x4){0.f, 0.f, 0.f, 0.f};

  int need = e - b;
  need = max(need, __shfl_xor(need, 16));
  need = max(need, __shfl_xor(need, 32));
  int iters = (need + 3) >> 2;
  int last = e - 1;

  // preload window-0 meta
  int idx[4]; float wgt[4];
  int t = b;
#pragma unroll
  for (int j = 0; j < 4; j++) {
    int tj = (t + j < e) ? t + j : last;            // clamped-safe, warm line
    int2 p = csr[tj];
    idx[j] = p.x;
    wgt[j] = (t + j < e) ? __int_as_float(p.y) : 0.f;
  }

  for (int it = 0; it < iters; it++, t += 4) {
    // scores for current window (S table is small -> L2-hot)
    float sv[4];
#pragma unroll
    for (int j = 0; j < 4; j++) sv[j] = Sc[idx[j]];
    // H row gathers for current window: unconditional, 8B/lane, 128B/row
    f32x4 hv[4];
#pragma unroll
    for (int j = 0; j < 4; j++) {
      ushort4 uv = *(const ushort4*)(Hb + (size_t)idx[j] * 64 + (fl << 2));
      hv[j][0] = __uint_as_float((unsigned)uv.x << 16);
      hv[j][1] = __uint_as_float((unsigned)uv.y << 16);
      hv[j][2] = __uint_as_float((unsigned)uv.z << 16);
      hv[j][3] = __uint_as_float((unsigned)uv.w << 16);
    }
    // prefetch next window's csr meta (clamped-safe; dummy on last iter)
    int idn[4]; float wgn[4];
#pragma unroll
    for (int j = 0; j < 4; j++) {
      int tj = (t + 4 + j < e) ? t + 4 + j : last;
      int2 p = csr[tj];
      idn[j] = p.x;
      wgn[j] = (t + 4 + j < e) ? __int_as_float(p.y) : 0.f;
    }
    // compute current window
    float ex[4];
#pragma unroll
    for (int j = 0; j < 4; j++)
      ex[j] = (t + j < e) ? __expf(leaky(sv[j] + dd)) : 0.f;
    den += (ex[0] + ex[1]) + (ex[2] + ex[3]);
    acc0 += hv[0] * (ex[0] * wgt[0]) + hv[1] * (ex[1] * wgt[1]);
    acc1 += hv[2] * (ex[2] * wgt[2]) + hv[3] * (ex[3] * wgt[3]);
    // rotate meta
#pragma unroll
    for (int j = 0; j < 4; j++) { idx[j] = idn[j]; wgt[j] = wgn[j]; }
  }

  float inv = 1.0f / fmaxf(den, 1e-16f);
  f32x4 o = (acc0 + acc1) * inv;
  if (RELU) {
#pragma unroll
    for (int j = 0; j < 4; j++) o[j] = fmaxf(o[j], 0.f);
  }
  if (SCORES) {                                    // layer-2 scores from f32 values
    f32x4 ws = *(const f32x4*)&WS[fl << 2];
    f32x4 wd = *(const f32x4*)&WD[fl << 2];
    float ps = o[0] * ws[0] + o[1] * ws[1] + o[2] * ws[2] + o[3] * ws[3];
    float pd = o[0] * wd[0] + o[1] * wd[1] + o[2] * wd[2] + o[3] * wd[3];
#pragma unroll
    for (int off = 1; off < 16; off <<= 1) {
      ps += __shfl_xor(ps, off);
      pd += __shfl_xor(pd, off);
    }
    if (active && fl == 0) { S2[node] = ps; D2[node] = pd; }
  }
  if (active) {
    if (OUTB16) {
      ushort4 st;
      st.x = bf_rne(o[0]); st.y = bf_rne(o[1]); st.z = bf_rne(o[2]); st.w = bf_rne(o[3]);
      *(ushort4*)((unsigned short*)OutV + (size_t)node * 64 + (fl << 2)) = st;
    } else {
      *(f32x4*)((float*)OutV + (size_t)node * 64 + (fl << 2)) = o;
    }
  }
}

// ---------------- launch ----------------
extern "C" void kernel_launch(void* const* d_in, const int* in_sizes, int n_in,
                              void* d_out, int out_size, void* d_ws, size_t ws_size,
                              hipStream_t stream) {
  const float* x   = (const float*)d_in[0];
  const int*   ei  = (const int*)d_in[1];
  const float* ew  = (const float*)d_in[2];
  const float* W1  = (const float*)d_in[3];
  const float* a1s = (const float*)d_in[4];
  const float* a1d = (const float*)d_in[5];
  const float* W2  = (const float*)d_in[6];
  const float* a2s = (const float*)d_in[7];
  const float* a2d = (const float*)d_in[8];

  const int HID = in_sizes[4];            // 64
  const int NC  = in_sizes[7];            // 40
  const int FIN = in_sizes[3] / HID;      // 256
  const int N   = in_sizes[0] / FIN;      // 100000
  const int E   = in_sizes[2];            // 1600000
  const int NT  = E + N;
  const int NB  = (N + 255) >> 8;         // 391 buckets
  float* out = (float*)d_out;

  char* wsb = (char*)d_ws;
  size_t off = 0;
  auto alloc = [&](size_t bytes) -> char* {
    char* p = wsb + off;
    off += (bytes + 255) & ~(size_t)255;
    return p;
  };
  unsigned short* h1b = (unsigned short*)alloc((size_t)N * 64 * 2);  // layer-1 bf16 image
  unsigned short* h2b = (unsigned short*)alloc((size_t)N * 64 * 2);  // layer-2 bf16 image
  float* A      = (float*)alloc((size_t)N * 64 * 4);   // layer-2 aggregated (pre-W2)
  float* S      = (float*)alloc((size_t)N * 4);
  float* D      = (float*)alloc((size_t)N * 4);
  float* S2     = (float*)alloc((size_t)N * 4);
  float* D2     = (float*)alloc((size_t)N * 4);
  int*   rp     = (int*)alloc((size_t)(N + 1) * 4);
  int*   bbase  = (int*)alloc((size_t)(NB + 1) * 4);
  int*   cursor = (int*)alloc((size_t)NB * 4);
  int2*  csr    = (int2*)alloc((size_t)NT * 8);
  int2*  staged = (int2*)alloc((size_t)NB * BCAP * 8);
  unsigned short* whi1 = (unsigned short*)alloc((size_t)FIN * 64 * 2);
  unsigned short* wlo1 = (unsigned short*)alloc((size_t)FIN * 64 * 2);
  unsigned short* whi2 = (unsigned short*)alloc((size_t)HID * 64 * 2);
  unsigned short* wlo2 = (unsigned short*)alloc((size_t)HID * 64 * 2);
  float* w2s = (float*)alloc((size_t)HID * 4);
  float* w2d = (float*)alloc((size_t)HID * 4);
  (void)ws_size; (void)n_in; (void)out_size;

  const int ebins = (NT + BIN_CHUNK - 1) / BIN_CHUNK;
  const int gblocks = (N + 63) / 64;
  const int ablocks = (N + 15) / 16;      // 16 nodes per 256-thread block
  const int nprep = ((FIN * 64) >> 8) + ((HID * 64) >> 8) + 1;

  hipLaunchKernelGGL(k_curinit, dim3((NB + 255) / 256), dim3(256), 0, stream, cursor, NB);
  hipLaunchKernelGGL(k_bin, dim3(ebins), dim3(256), 0, stream, ei, ew, E, N, cursor, staged, NB);
  hipLaunchKernelGGL(k_bscan, dim3(1), dim3(512), 0, stream, cursor, NB, NT, N, bbase, rp);
  hipLaunchKernelGGL(k_finalize, dim3(NB), dim3(512), 0, stream, staged, bbase, N, rp, csr);

  // merged weight prep (was 3 launches: wprep x2 + wvec)
  hipLaunchKernelGGL(k_prep, dim3(nprep), dim3(256), 0, stream,
                     W1, W2, a2s, a2d, FIN, HID, NC,
                     whi1, wlo1, whi2, wlo2, w2s, w2d);

  // ---- layer 1: h1b(bf16) = x@W1 + scores S,D ----
  hipLaunchKernelGGL(k_gemm_mfma, dim3(gblocks), dim3(256), 0, stream,
                     x, FIN, whi1, wlo1, a1s, a1d, HID, (float*)nullptr, h1b, 64, S, D, N);
  // ---- agg1: softmax-aggregate h1b -> h2b(bf16, ReLU); fused layer-2 scores S2,D2 ----
  hipLaunchKernelGGL((k_agg<true, true, true>), dim3(ablocks), dim3(256), 0, stream,
                     rp, csr, S, D, h1b, (void*)h2b, w2s, w2d, S2, D2, N);
  // ---- agg2: softmax-aggregate h2b -> A(f32, 64 cols); W2 commuted past the sum ----
  hipLaunchKernelGGL((k_agg<false, false, false>), dim3(ablocks), dim3(256), 0, stream,
                     rp, csr, S2, D2, h2b, (void*)A, (const float*)nullptr,
                     (const float*)nullptr, (float*)nullptr, (float*)nullptr, N);
  // ---- out = A @ W2 (dense MFMA, K=64; S/D scratch writes ignored) ----
  hipLaunchKernelGGL(k_gemm_mfma, dim3(gblocks), dim3(256), 0, stream,
                     A, HID, whi2, wlo2, a2s, a2d, NC, out, (unsigned short*)nullptr, NC, S, D, N);
}

// Round 10
// 349.838 us; speedup vs baseline: 1.2940x; 1.0115x over previous
//
#include <hip/hip_runtime.h>
#include <hip/hip_bf16.h>
#include <math.h>

#define NEG_SLOPE 0.2f

typedef __attribute__((ext_vector_type(4))) float f32x4;
typedef __attribute__((ext_vector_type(8))) short bf16x8;
typedef __attribute__((ext_vector_type(4))) short bf16x4;

__device__ __forceinline__ float leaky(float x) { return x > 0.f ? x : NEG_SLOPE * x; }

__device__ __forceinline__ unsigned short bf_hi(float x) {
  return (unsigned short)(__float_as_uint(x) >> 16);  // truncation split (exact residual)
}

__device__ __forceinline__ unsigned short bf_rne(float x) {
  unsigned u = __float_as_uint(x);
  return (unsigned short)((u + 0x7FFFu + ((u >> 16) & 1u)) >> 16);  // round-nearest-even
}

// ---------------- CSR build: bucket-local, fixed-capacity staging ----------------

#define BIN_CHUNK 2048
#define BCAP 8192

__global__ void k_curinit(int* __restrict__ cursor, int NB) {
  int i = blockIdx.x * blockDim.x + threadIdx.x;
  if (i < NB) cursor[i] = i * BCAP;
}

// stage edges bucket-contiguously; entry = (src | dstlow<<24, weight_bits)
__global__ __launch_bounds__(256)
void k_bin(const int* __restrict__ ei, const float* __restrict__ ew, int E, int N,
           int* __restrict__ cursor, int2* __restrict__ staged, int NB) {
  __shared__ int lhist[512];
  __shared__ int lbase[512];
  int tid = threadIdx.x;
  int start = blockIdx.x * BIN_CHUNK;
  int NT = E + N;
  int srcv[8], dstv[8]; float wv[8];
#pragma unroll
  for (int j = 0; j < 8; j++) {
    int e = start + j * 256 + tid;       // coalesced
    int s = 0, d = -1; float w = 0.f;
    if (e < NT) {
      if (e < E) { s = ei[e]; d = ei[E + e]; w = ew[e]; }
      else       { s = d = e - E; w = 1.f; }   // self-loop
    }
    srcv[j] = s; dstv[j] = d; wv[j] = w;
  }
  for (int b = tid; b < NB; b += 256) lhist[b] = 0;
  __syncthreads();
#pragma unroll
  for (int j = 0; j < 8; j++)
    if (dstv[j] >= 0) atomicAdd(&lhist[dstv[j] >> 8], 1);
  __syncthreads();
  for (int b = tid; b < NB; b += 256) {
    int n = lhist[b];
    lbase[b] = (n > 0) ? atomicAdd(&cursor[b], n) : 0;
    lhist[b] = 0;
  }
  __syncthreads();
#pragma unroll
  for (int j = 0; j < 8; j++) {
    if (dstv[j] >= 0) {
      int bkt = dstv[j] >> 8;
      int off = atomicAdd(&lhist[bkt], 1);          // LDS cursor
      staged[lbase[bkt] + off] =
          make_int2(srcv[j] | ((dstv[j] & 255) << 24), __float_as_int(wv[j]));
    }
  }
}

// totals from cursor deltas -> parallel exclusive scan -> packed bases
__global__ __launch_bounds__(512)
void k_bscan(const int* __restrict__ cursor, int NB, int NT, int N,
             int* __restrict__ bbase, int* __restrict__ rp) {
  __shared__ int sm[512];
  int tid = threadIdx.x;                           // 512 threads, NB <= 512
  int v = (tid < NB) ? cursor[tid] - tid * BCAP : 0;
  sm[tid] = v;
  __syncthreads();
  for (int off = 1; off < 512; off <<= 1) {        // Hillis-Steele inclusive
    int x = sm[tid];
    int a = (tid >= off) ? sm[tid - off] : 0;
    __syncthreads();
    sm[tid] = x + a;
    __syncthreads();
  }
  if (tid < NB) bbase[tid] = sm[tid] - v;          // exclusive
  if (tid == 0) { bbase[NB] = sm[NB - 1]; rp[N] = NT; }
}

// one block per bucket: LDS count -> scan -> rp -> LDS-cursor scatter to packed csr
__global__ __launch_bounds__(512)
void k_finalize(const int2* __restrict__ staged, const int* __restrict__ bbase,
                int N, int* __restrict__ rp, int2* __restrict__ csr) {
  __shared__ int cnt[256];
  __shared__ int sm[256];
  int b = blockIdx.x, tid = threadIdx.x;
  int sbase = b * BCAP;
  int cbase = bbase[b];
  int size = bbase[b + 1] - cbase;
  if (tid < 256) cnt[tid] = 0;
  __syncthreads();
  for (int i = tid; i < size; i += 512) {
    int2 v = staged[sbase + i];
    atomicAdd(&cnt[((unsigned)v.x) >> 24], 1);
  }
  __syncthreads();
  int s = 0;
  if (tid < 256) { s = cnt[tid]; sm[tid] = s; }
  __syncthreads();
  for (int off = 1; off < 256; off <<= 1) {        // Hillis-Steele inclusive scan
    int x = 0;
    if (tid < 256) { x = sm[tid]; if (tid >= off) x += sm[tid - off]; }
    __syncthreads();
    if (tid < 256) sm[tid] = x;
    __syncthreads();
  }
  if (tid < 256) {
    int excl = sm[tid] - s;
    int node = (b << 8) + tid;
    if (node < N) rp[node] = cbase + excl;
    cnt[tid] = excl;                               // becomes the scatter cursor
  }
  __syncthreads();
  for (int i = tid; i < size; i += 512) {
    int2 v = staged[sbase + i];
    int dlow = ((unsigned)v.x) >> 24;
    int pos = cbase + atomicAdd(&cnt[dlow], 1);    // LDS atomic
    csr[pos] = make_int2(v.x & 0x00FFFFFF, v.y);
  }
}

// ---------------- merged weight prep: W1/W2 bf16 hi/lo images + w2s/w2d vectors ------
__device__ __forceinline__ void wprep_one(const float* __restrict__ W, int idx, int Mout,
                                          unsigned short* __restrict__ whi,
                                          unsigned short* __restrict__ wlo) {
  int k = idx >> 6, n = idx & 63;
  float v = (n < Mout) ? W[(size_t)k * Mout + n] : 0.f;
  unsigned short h = bf_hi(v);
  float hf = __uint_as_float((unsigned)h << 16);
  unsigned short l = bf_hi(v - hf);
  int kc = k >> 5, kk = k & 31, quad = kk >> 3, j = kk & 7;
  int ct = n >> 4, nn = n & 15;
  int off = (((kc * 4 + ct) * 64) + quad * 16 + nn) * 8 + j;
  whi[off] = h; wlo[off] = l;
}

__global__ __launch_bounds__(256)
void k_prep(const float* __restrict__ W1, const float* __restrict__ W2,
            const float* __restrict__ a2s, const float* __restrict__ a2d,
            int FIN, int HID, int NC,
            unsigned short* __restrict__ whi1, unsigned short* __restrict__ wlo1,
            unsigned short* __restrict__ whi2, unsigned short* __restrict__ wlo2,
            float* __restrict__ w2s, float* __restrict__ w2d) {
  int blk = blockIdx.x, tid = threadIdx.x;
  int nb1 = (FIN * 64) >> 8;                       // 64 blocks for W1
  int nb2 = (HID * 64) >> 8;                       // 16 blocks for W2
  if (blk < nb1) {
    wprep_one(W1, blk * 256 + tid, HID, whi1, wlo1);
  } else if (blk < nb1 + nb2) {
    wprep_one(W2, (blk - nb1) * 256 + tid, NC, whi2, wlo2);
  } else {
    if (tid < HID) {                               // w2s = W2@a2s, w2d = W2@a2d
      float s = 0.f, d = 0.f;
      for (int n = 0; n < NC; n++) {
        float w = W2[(size_t)tid * NC + n];
        s += w * a2s[n]; d += w * a2d[n];
      }
      w2s[tid] = s; w2d[tid] = d;
    }
  }
}

// ---------------- MFMA GEMM (split-bf16) + optional fused attention scores -----------
// NCT: number of 16-col output tiles computed (4 -> 64 cols, 3 -> 48 cols).
// EMIT_SD: compute + write per-row scores S,D (layer 1); false skips the whole
//          shuffle-reduce epilogue chain (layer 2's S/D were discarded scratch).
// OUTB16: write bf16 image Hb (layer 1) vs f32 Hf (layer 2 -> out).
template <int NCT, bool EMIT_SD, bool OUTB16>
__global__ __launch_bounds__(256)
void k_gemm_mfma(const float* __restrict__ X, int K,
                 const unsigned short* __restrict__ WHI, const unsigned short* __restrict__ WLO,
                 const float* __restrict__ ASRC, const float* __restrict__ ADST, int Mout,
                 float* __restrict__ Hf, unsigned short* __restrict__ Hb, int ldH,
                 float* __restrict__ S, float* __restrict__ D, int N) {
  __shared__ __align__(16) unsigned short xhi[2048], xlo[2048];   // 4 rowtiles*64 lanes*8
  __shared__ __align__(16) unsigned short whs[2048], wls[2048];   // 4 coltiles*64 lanes*8
  int tid = threadIdx.x;
  int lane = tid & 63, w = tid >> 6;
  int rowBase = blockIdx.x * 64;

  f32x4 acc[NCT];
#pragma unroll
  for (int c = 0; c < NCT; c++) acc[c] = (f32x4){0.f, 0.f, 0.f, 0.f};

  int q0 = tid, q1 = tid + 256;
  int row0 = q0 >> 3, k40 = (q0 & 7) << 2;
  int row1 = q1 >> 3, k41 = (q1 & 7) << 2;
  int xo0 = (((row0 >> 4) * 64) + (k40 >> 3) * 16 + (row0 & 15)) * 8 + (k40 & 7);
  int xo1 = (((row1 >> 4) * 64) + (k41 >> 3) * 16 + (row1 & 15)) * 8 + (k41 & 7);
  int grow0 = rowBase + row0, grow1 = rowBase + row1;

  int nch = K >> 5;
  f32x4 xr0, xr1; bf16x8 wh, wl;

  xr0 = (f32x4){0.f, 0.f, 0.f, 0.f}; xr1 = xr0;
  if (grow0 < N) xr0 = *(const f32x4*)&X[(size_t)grow0 * K + k40];
  if (grow1 < N) xr1 = *(const f32x4*)&X[(size_t)grow1 * K + k41];
  wh = *(const bf16x8*)(WHI + tid * 8);
  wl = *(const bf16x8*)(WLO + tid * 8);

  for (int kc = 0; kc < nch; kc++) {
    bf16x4 h4, l4;
#pragma unroll
    for (int i = 0; i < 4; i++) {
      unsigned short h = bf_hi(xr0[i]);
      float hf = __uint_as_float((unsigned)h << 16);
      h4[i] = (short)h; l4[i] = (short)bf_hi(xr0[i] - hf);
    }
    *(bf16x4*)(xhi + xo0) = h4; *(bf16x4*)(xlo + xo0) = l4;
#pragma unroll
    for (int i = 0; i < 4; i++) {
      unsigned short h = bf_hi(xr1[i]);
      float hf = __uint_as_float((unsigned)h << 16);
      h4[i] = (short)h; l4[i] = (short)bf_hi(xr1[i] - hf);
    }
    *(bf16x4*)(xhi + xo1) = h4; *(bf16x4*)(xlo + xo1) = l4;
    *(bf16x8*)(whs + tid * 8) = wh;
    *(bf16x8*)(wls + tid * 8) = wl;
    __syncthreads();

    if (kc + 1 < nch) {
      int kb = (kc + 1) << 5;
      xr0 = (f32x4){0.f, 0.f, 0.f, 0.f}; xr1 = xr0;
      if (grow0 < N) xr0 = *(const f32x4*)&X[(size_t)grow0 * K + kb + k40];
      if (grow1 < N) xr1 = *(const f32x4*)&X[(size_t)grow1 * K + kb + k41];
      wh = *(const bf16x8*)(WHI + (size_t)(kc + 1) * 2048 + tid * 8);
      wl = *(const bf16x8*)(WLO + (size_t)(kc + 1) * 2048 + tid * 8);
    }

    bf16x8 ah = *(const bf16x8*)(xhi + (w * 64 + lane) * 8);
    bf16x8 al = *(const bf16x8*)(xlo + (w * 64 + lane) * 8);
#pragma unroll
    for (int c = 0; c < NCT; c++) {
      bf16x8 bh = *(const bf16x8*)(whs + (c * 64 + lane) * 8);
      bf16x8 bl = *(const bf16x8*)(wls + (c * 64 + lane) * 8);
      acc[c] = __builtin_amdgcn_mfma_f32_16x16x32_bf16(ah, bh, acc[c], 0, 0, 0);
      acc[c] = __builtin_amdgcn_mfma_f32_16x16x32_bf16(ah, bl, acc[c], 0, 0, 0);
      acc[c] = __builtin_amdgcn_mfma_f32_16x16x32_bf16(al, bh, acc[c], 0, 0, 0);
    }
    __syncthreads();
  }

  int nn = lane & 15, quad = lane >> 4;
  float as_[NCT], ad_[NCT];
  if (EMIT_SD) {
#pragma unroll
    for (int c = 0; c < NCT; c++) {
      int col = c * 16 + nn;
      as_[c] = (col < Mout) ? ASRC[col] : 0.f;
      ad_[c] = (col < Mout) ? ADST[col] : 0.f;
    }
  }
#pragma unroll
  for (int r = 0; r < 4; r++) {
    int grow = rowBase + w * 16 + quad * 4 + r;
    float ps = 0.f, pd = 0.f;
#pragma unroll
    for (int c = 0; c < NCT; c++) {
      float v = acc[c][r];
      int col = c * 16 + nn;
      if (grow < N && col < Mout) {
        if (OUTB16) Hb[(size_t)grow * ldH + col] = bf_rne(v);
        else        Hf[(size_t)grow * ldH + col] = v;
      }
      if (EMIT_SD) { ps += v * as_[c]; pd += v * ad_[c]; }
    }
    if (EMIT_SD) {
#pragma unroll
      for (int off = 1; off < 16; off <<= 1) {
        ps += __shfl_xor(ps, off);
        pd += __shfl_xor(pd, off);
      }
      if (nn == 0 && grow < N) { S[grow] = ps; D[grow] = pd; }
    }
  }
}

// ---------------- fused aggregation: no-max softmax, branch-free, pipelined ----------
// R4/R9's measured-best shape: 4 nodes per wave, 16 lanes each, depth 4, csr meta
// prefetched one window ahead, all loads unconditional clamped-safe, masking on
// values only. (Depth 8 regressed twice: R2 branchy, R8 occupancy collapse.)
template <bool OUTB16, bool RELU, bool SCORES>
__global__ __launch_bounds__(256)
void k_agg(const int* __restrict__ rp, const int2* __restrict__ csr,
           const float* __restrict__ Sc, const float* __restrict__ Dc,
           const unsigned short* __restrict__ Hb, void* __restrict__ OutV,
           const float* __restrict__ WS, const float* __restrict__ WD,
           float* __restrict__ S2, float* __restrict__ D2, int N) {
  int gw = (blockIdx.x * blockDim.x + threadIdx.x) >> 6;
  int lane = threadIdx.x & 63;
  int sub = lane >> 4, fl = lane & 15;
  int node = gw * 4 + sub;
  bool active = node < N;
  int b = 0, e = 1; float dd = 0.f;
  if (active) { b = rp[node]; e = rp[node + 1]; dd = Dc[node]; }
  float den = 0.f;
  f32x4 acc0 = (f32x4){0.f, 0.f, 0.f, 0.f};
  f32x4 acc1 = (f32x4){0.f, 0.f, 0.f, 0.f};

  int need = e - b;
  need = max(need, __shfl_xor(need, 16));
  need = max(need, __shfl_xor(need, 32));
  int iters = (need + 3) >> 2;
  int last = e - 1;

  // preload window-0 meta
  int idx[4]; float wgt[4];
  int t = b;
#pragma unroll
  for (int j = 0; j < 4; j++) {
    int tj = (t + j < e) ? t + j : last;            // clamped-safe, warm line
    int2 p = csr[tj];
    idx[j] = p.x;
    wgt[j] = (t + j < e) ? __int_as_float(p.y) : 0.f;
  }

  for (int it = 0; it < iters; it++, t += 4) {
    // scores for current window (S table is small -> L2-hot)
    float sv[4];
#pragma unroll
    for (int j = 0; j < 4; j++) sv[j] = Sc[idx[j]];
    // H row gathers for current window: unconditional, 8B/lane, 128B/row
    f32x4 hv[4];
#pragma unroll
    for (int j = 0; j < 4; j++) {
      ushort4 uv = *(const ushort4*)(Hb + (size_t)idx[j] * 64 + (fl << 2));
      hv[j][0] = __uint_as_float((unsigned)uv.x << 16);
      hv[j][1] = __uint_as_float((unsigned)uv.y << 16);
      hv[j][2] = __uint_as_float((unsigned)uv.z << 16);
      hv[j][3] = __uint_as_float((unsigned)uv.w << 16);
    }
    // prefetch next window's csr meta (clamped-safe; dummy on last iter)
    int idn[4]; float wgn[4];
#pragma unroll
    for (int j = 0; j < 4; j++) {
      int tj = (t + 4 + j < e) ? t + 4 + j : last;
      int2 p = csr[tj];
      idn[j] = p.x;
      wgn[j] = (t + 4 + j < e) ? __int_as_float(p.y) : 0.f;
    }
    // compute current window
    float ex[4];
#pragma unroll
    for (int j = 0; j < 4; j++)
      ex[j] = (t + j < e) ? __expf(leaky(sv[j] + dd)) : 0.f;
    den += (ex[0] + ex[1]) + (ex[2] + ex[3]);
    acc0 += hv[0] * (ex[0] * wgt[0]) + hv[1] * (ex[1] * wgt[1]);
    acc1 += hv[2] * (ex[2] * wgt[2]) + hv[3] * (ex[3] * wgt[3]);
    // rotate meta
#pragma unroll
    for (int j = 0; j < 4; j++) { idx[j] = idn[j]; wgt[j] = wgn[j]; }
  }

  float inv = 1.0f / fmaxf(den, 1e-16f);
  f32x4 o = (acc0 + acc1) * inv;
  if (RELU) {
#pragma unroll
    for (int j = 0; j < 4; j++) o[j] = fmaxf(o[j], 0.f);
  }
  if (SCORES) {                                    // layer-2 scores from f32 values
    f32x4 ws = *(const f32x4*)&WS[fl << 2];
    f32x4 wd = *(const f32x4*)&WD[fl << 2];
    float ps = o[0] * ws[0] + o[1] * ws[1] + o[2] * ws[2] + o[3] * ws[3];
    float pd = o[0] * wd[0] + o[1] * wd[1] + o[2] * wd[2] + o[3] * wd[3];
#pragma unroll
    for (int off = 1; off < 16; off <<= 1) {
      ps += __shfl_xor(ps, off);
      pd += __shfl_xor(pd, off);
    }
    if (active && fl == 0) { S2[node] = ps; D2[node] = pd; }
  }
  if (active) {
    if (OUTB16) {
      ushort4 st;
      st.x = bf_rne(o[0]); st.y = bf_rne(o[1]); st.z = bf_rne(o[2]); st.w = bf_rne(o[3]);
      *(ushort4*)((unsigned short*)OutV + (size_t)node * 64 + (fl << 2)) = st;
    } else {
      *(f32x4*)((float*)OutV + (size_t)node * 64 + (fl << 2)) = o;
    }
  }
}

// ---------------- launch ----------------
extern "C" void kernel_launch(void* const* d_in, const int* in_sizes, int n_in,
                              void* d_out, int out_size, void* d_ws, size_t ws_size,
                              hipStream_t stream) {
  const float* x   = (const float*)d_in[0];
  const int*   ei  = (const int*)d_in[1];
  const float* ew  = (const float*)d_in[2];
  const float* W1  = (const float*)d_in[3];
  const float* a1s = (const float*)d_in[4];
  const float* a1d = (const float*)d_in[5];
  const float* W2  = (const float*)d_in[6];
  const float* a2s = (const float*)d_in[7];
  const float* a2d = (const float*)d_in[8];

  const int HID = in_sizes[4];            // 64
  const int NC  = in_sizes[7];            // 40
  const int FIN = in_sizes[3] / HID;      // 256
  const int N   = in_sizes[0] / FIN;      // 100000
  const int E   = in_sizes[2];            // 1600000
  const int NT  = E + N;
  const int NB  = (N + 255) >> 8;         // 391 buckets
  float* out = (float*)d_out;

  char* wsb = (char*)d_ws;
  size_t off = 0;
  auto alloc = [&](size_t bytes) -> char* {
    char* p = wsb + off;
    off += (bytes + 255) & ~(size_t)255;
    return p;
  };
  unsigned short* h1b = (unsigned short*)alloc((size_t)N * 64 * 2);  // layer-1 bf16 image
  unsigned short* h2b = (unsigned short*)alloc((size_t)N * 64 * 2);  // layer-2 bf16 image
  float* A      = (float*)alloc((size_t)N * 64 * 4);   // layer-2 aggregated (pre-W2)
  float* S      = (float*)alloc((size_t)N * 4);
  float* D      = (float*)alloc((size_t)N * 4);
  float* S2     = (float*)alloc((size_t)N * 4);
  float* D2     = (float*)alloc((size_t)N * 4);
  int*   rp     = (int*)alloc((size_t)(N + 1) * 4);
  int*   bbase  = (int*)alloc((size_t)(NB + 1) * 4);
  int*   cursor = (int*)alloc((size_t)NB * 4);
  int2*  csr    = (int2*)alloc((size_t)NT * 8);
  int2*  staged = (int2*)alloc((size_t)NB * BCAP * 8);
  unsigned short* whi1 = (unsigned short*)alloc((size_t)FIN * 64 * 2);
  unsigned short* wlo1 = (unsigned short*)alloc((size_t)FIN * 64 * 2);
  unsigned short* whi2 = (unsigned short*)alloc((size_t)HID * 64 * 2);
  unsigned short* wlo2 = (unsigned short*)alloc((size_t)HID * 64 * 2);
  float* w2s = (float*)alloc((size_t)HID * 4);
  float* w2d = (float*)alloc((size_t)HID * 4);
  (void)ws_size; (void)n_in; (void)out_size;

  const int ebins = (NT + BIN_CHUNK - 1) / BIN_CHUNK;
  const int gblocks = (N + 63) / 64;
  const int ablocks = (N + 15) / 16;      // 16 nodes per 256-thread block
  const int nprep = ((FIN * 64) >> 8) + ((HID * 64) >> 8) + 1;

  hipLaunchKernelGGL(k_curinit, dim3((NB + 255) / 256), dim3(256), 0, stream, cursor, NB);
  hipLaunchKernelGGL(k_bin, dim3(ebins), dim3(256), 0, stream, ei, ew, E, N, cursor, staged, NB);
  hipLaunchKernelGGL(k_bscan, dim3(1), dim3(512), 0, stream, cursor, NB, NT, N, bbase, rp);
  hipLaunchKernelGGL(k_finalize, dim3(NB), dim3(512), 0, stream, staged, bbase, N, rp, csr);

  // merged weight prep (wprep x2 + wvec in one launch)
  hipLaunchKernelGGL(k_prep, dim3(nprep), dim3(256), 0, stream,
                     W1, W2, a2s, a2d, FIN, HID, NC,
                     whi1, wlo1, whi2, wlo2, w2s, w2d);

  // ---- layer 1: h1b(bf16) = x@W1 + scores S,D (4 col-tiles, full epilogue) ----
  hipLaunchKernelGGL((k_gemm_mfma<4, true, true>), dim3(gblocks), dim3(256), 0, stream,
                     x, FIN, whi1, wlo1, a1s, a1d, HID, (float*)nullptr, h1b, 64, S, D, N);
  // ---- agg1: softmax-aggregate h1b -> h2b(bf16, ReLU); fused layer-2 scores S2,D2 ----
  hipLaunchKernelGGL((k_agg<true, true, true>), dim3(ablocks), dim3(256), 0, stream,
                     rp, csr, S, D, h1b, (void*)h2b, w2s, w2d, S2, D2, N);
  // ---- agg2: softmax-aggregate h2b -> A(f32, 64 cols); W2 commuted past the sum ----
  hipLaunchKernelGGL((k_agg<false, false, false>), dim3(ablocks), dim3(256), 0, stream,
                     rp, csr, S2, D2, h2b, (void*)A, (const float*)nullptr,
                     (const float*)nullptr, (float*)nullptr, (float*)nullptr, N);
  // ---- out = A @ W2 (3 col-tiles cover 40 cols; no S/D epilogue) ----
  hipLaunchKernelGGL((k_gemm_mfma<3, false, false>), dim3(gblocks), dim3(256), 0, stream,
                     A, HID, whi2, wlo2, a2s, a2d, NC, out, (unsigned short*)nullptr, NC,
                     (float*)nullptr, (float*)nullptr, N);
}